// Round 1
// baseline (221.258 us; speedup 1.0000x reference)
//
#include <hip/hip_runtime.h>

#define POOL_H 7
#define POOL_W 7
#define SR 2            // sampling ratio
#define SCALE 0.25f

// One thread per output element (k, c, ph, pw).
// Output layout (from reference transpose): out[k][c][ph][pw], linear = idx.
__global__ __launch_bounds__(256) void roi_align_kernel(
    const float* __restrict__ feat,   // [N][C][H][W]
    const float* __restrict__ rois,   // [K][5]
    float* __restrict__ out,          // [K][C][POOL_H][POOL_W]
    int C, int H, int W, int K)
{
    int idx = blockIdx.x * blockDim.x + threadIdx.x;
    int total = K * C * POOL_H * POOL_W;
    if (idx >= total) return;

    int pw = idx % POOL_W;
    int ph = (idx / POOL_W) % POOL_H;
    int c  = (idx / (POOL_W * POOL_H)) % C;
    int k  = idx / (POOL_W * POOL_H * C);

    const float* r = rois + (size_t)k * 5;
    int b = (int)r[0];
    float x1 = r[1] * SCALE - 0.5f;
    float y1 = r[2] * SCALE - 0.5f;
    float x2 = r[3] * SCALE - 0.5f;
    float y2 = r[4] * SCALE - 0.5f;
    float bin_h = (y2 - y1) * (1.0f / POOL_H);
    float bin_w = (x2 - x1) * (1.0f / POOL_W);

    const float* fmap = feat + ((size_t)b * C + c) * (size_t)(H * W);

    float acc = 0.0f;
    #pragma unroll
    for (int iy = 0; iy < SR; ++iy) {
        float y = y1 + ((float)ph + ((float)iy + 0.5f) * (1.0f / SR)) * bin_h;
        bool vy = (y > -1.0f) && (y < (float)H);
        float yc = fminf(fmaxf(y, 0.0f), (float)(H - 1));
        int   yi0 = (int)floorf(yc);
        int   yi1 = min(yi0 + 1, H - 1);
        float ly = yc - (float)yi0;
        float hy = 1.0f - ly;
        #pragma unroll
        for (int ix = 0; ix < SR; ++ix) {
            float x = x1 + ((float)pw + ((float)ix + 0.5f) * (1.0f / SR)) * bin_w;
            bool vx = (x > -1.0f) && (x < (float)W);
            if (!(vy && vx)) continue;   // reference: where(valid, val, 0)
            float xc = fminf(fmaxf(x, 0.0f), (float)(W - 1));
            int   xi0 = (int)floorf(xc);
            int   xi1 = min(xi0 + 1, W - 1);
            float lx = xc - (float)xi0;
            float hx = 1.0f - lx;

            float v00 = fmap[yi0 * W + xi0];
            float v01 = fmap[yi0 * W + xi1];
            float v10 = fmap[yi1 * W + xi0];
            float v11 = fmap[yi1 * W + xi1];

            acc += hy * hx * v00 + hy * lx * v01
                 + ly * hx * v10 + ly * lx * v11;
        }
    }
    out[idx] = acc * (1.0f / (SR * SR));
}

extern "C" void kernel_launch(void* const* d_in, const int* in_sizes, int n_in,
                              void* d_out, int out_size, void* d_ws, size_t ws_size,
                              hipStream_t stream) {
    const float* feat = (const float*)d_in[0];
    const float* rois = (const float*)d_in[1];
    float* out = (float*)d_out;

    // feat: N*C*H*W with N=4, C=256, H=W=200; rois: K*5
    const int C = 256, H = 200, W = 200;
    const int K = in_sizes[1] / 5;

    int total = K * C * POOL_H * POOL_W;
    int block = 256;
    int grid = (total + block - 1) / block;
    roi_align_kernel<<<grid, block, 0, stream>>>(feat, rois, out, C, H, W, K);
}